// Round 3
// baseline (193.530 us; speedup 1.0000x reference)
//
#include <hip/hip_runtime.h>

typedef __bf16 bf16x8 __attribute__((ext_vector_type(8)));
typedef __bf16 bf16x4 __attribute__((ext_vector_type(4)));
typedef float  f32x4  __attribute__((ext_vector_type(4)));

constexpr int B_ = 4, S_ = 1024, D_ = 768, N_ = 12, H_ = 64;
constexpr int BNSH = B_ * N_ * S_ * H_;   // 3,145,728
constexpr float SCALE2 = 0.18033688011f;  // (1/sqrt(64)) * log2(e): exp2 domain

__device__ __forceinline__ f32x4 mfma16(bf16x8 a, bf16x8 b, f32x4 c) {
    return __builtin_amdgcn_mfma_f32_16x16x32_bf16(a, b, c, 0, 0, 0);
}

// async global->LDS, 16B per lane. HW dest = wave-uniform base + lane*16.
__device__ __forceinline__ void gload16(const __bf16* g, __bf16* l) {
    __builtin_amdgcn_global_load_lds(
        (const __attribute__((address_space(1))) unsigned int*)g,
        (__attribute__((address_space(3))) unsigned int*)l, 16, 0, 0);
}

// ---- LDS tile staging with 16B-chunk xor swizzle --------------------------
// Tiles are [rows][64] bf16. Global chunk (r, q) lands at LDS slot (r, q^(r&7)).
__device__ __forceinline__ void stage128x64(const __bf16* g, int ld, __bf16* lds,
                                            int wid, int lane) {
    #pragma unroll
    for (int i = 0; i < 4; ++i) {
        int cb = (wid * 4 + i) * 64;
        int chunk = cb + lane;
        int r = chunk >> 3, p = chunk & 7;
        int q = p ^ (r & 7);
        gload16(g + (size_t)r * ld + q * 8, lds + cb * 8);
    }
}
__device__ __forceinline__ void stage64x64(const __bf16* g, int ld, __bf16* lds,
                                           int wid, int lane) {
    #pragma unroll
    for (int i = 0; i < 2; ++i) {
        int cb = (wid * 2 + i) * 64;
        int chunk = cb + lane;
        int r = chunk >> 3, p = chunk & 7;
        int q = p ^ (r & 7);
        gload16(g + (size_t)r * ld + q * 8, lds + cb * 8);
    }
}
__device__ __forceinline__ bf16x8 frag(const __bf16* lds, int row, int kc) {
    int p = kc ^ (row & 7);
    return *(const bf16x8*)(lds + row * 64 + p * 8);
}

// ---------------------------------------------------------------------------
// Fused prep: cast x -> bf16; transpose-cast W_QKV -> [2304][768]; W_O -> B^T.
// blocks [0,768): x cast; [768,1200): wqkv; [1200,1344): wo.
// ---------------------------------------------------------------------------
__global__ __launch_bounds__(256) void prep_kernel(
    const float* __restrict__ x,
    const float* __restrict__ wq, const float* __restrict__ wk,
    const float* __restrict__ wv, const float* __restrict__ wo,
    __bf16* __restrict__ xb, __bf16* __restrict__ wt, __bf16* __restrict__ wot) {
    __shared__ __bf16 T[64][65];
    const int blk = blockIdx.x;
    const int tid = threadIdx.x;
    if (blk < 768) {
        int base = blk * 1024 + tid;
        #pragma unroll
        for (int i = 0; i < 4; ++i) {
            int idx = base + i * 256;
            float4 v = ((const float4*)x)[idx];
            bf16x4 o;
            o[0] = (__bf16)v.x; o[1] = (__bf16)v.y;
            o[2] = (__bf16)v.z; o[3] = (__bf16)v.w;
            ((bf16x4*)xb)[idx] = o;
        }
        return;
    }
    int rr = tid >> 4, c4 = (tid & 15) * 4;
    if (blk < 1200) {
        int t = blk - 768;
        int dt = t % 12, mh = t / 12;
        int mat = mh / 12, n = mh % 12;
        const float* in = (mat == 0 ? wq : mat == 1 ? wk : wv) + (size_t)n * 768 * 64;
        __bf16* outp = wt + (size_t)(mat * 768 + n * 64) * 768;
        int d0 = dt * 64;
        #pragma unroll
        for (int i = 0; i < 4; ++i) {
            int row = rr + 16 * i;
            float4 v = *(const float4*)&in[(size_t)(d0 + row) * 64 + c4];
            T[c4 + 0][row] = (__bf16)v.x;
            T[c4 + 1][row] = (__bf16)v.y;
            T[c4 + 2][row] = (__bf16)v.z;
            T[c4 + 3][row] = (__bf16)v.w;
        }
        __syncthreads();
        #pragma unroll
        for (int i = 0; i < 4; ++i) {
            int hrow = rr + 16 * i;
            bf16x4 o;
            o[0] = T[hrow][c4 + 0]; o[1] = T[hrow][c4 + 1];
            o[2] = T[hrow][c4 + 2]; o[3] = T[hrow][c4 + 3];
            *(bf16x4*)&outp[(size_t)hrow * 768 + d0 + c4] = o;
        }
    } else {
        int t = blk - 1200;
        int r0 = (t % 12) * 64, c0 = (t / 12) * 64;
        #pragma unroll
        for (int i = 0; i < 4; ++i) {
            int row = rr + 16 * i;
            float4 v = *(const float4*)&wo[(size_t)(r0 + row) * 768 + c0 + c4];
            T[c4 + 0][row] = (__bf16)v.x;
            T[c4 + 1][row] = (__bf16)v.y;
            T[c4 + 2][row] = (__bf16)v.z;
            T[c4 + 3][row] = (__bf16)v.w;
        }
        __syncthreads();
        #pragma unroll
        for (int i = 0; i < 4; ++i) {
            int crow = rr + 16 * i;
            bf16x4 o;
            o[0] = T[crow][c4 + 0]; o[1] = T[crow][c4 + 1];
            o[2] = T[crow][c4 + 2]; o[3] = T[crow][c4 + 3];
            *(bf16x4*)&wot[(size_t)(c0 + crow) * 768 + r0 + c4] = o;
        }
    }
}

// ---------------------------------------------------------------------------
// QKV GEMM (unchanged): 128x128 tile, BK=64.
// Writes Q,K as [B,N,S,H] bf16; V transposed as [B,N,H,S] bf16.
// ---------------------------------------------------------------------------
__global__ __launch_bounds__(256) void qkv_gemm(
    const __bf16* __restrict__ xb, const __bf16* __restrict__ wtg,
    const float* __restrict__ bq, const float* __restrict__ bk,
    const float* __restrict__ bv,
    __bf16* __restrict__ Qb, __bf16* __restrict__ Kb, __bf16* __restrict__ Vtb) {
    __shared__ __bf16 As[128 * 64];
    __shared__ __bf16 Bs[128 * 64];
    const int m0 = blockIdx.x * 128;
    const int j0 = blockIdx.y * 128;
    const int tid = threadIdx.x, wid = tid >> 6, lane = tid & 63;
    const int quad = lane >> 4, lrow = lane & 15;
    const int wr = wid & 1, wc = wid >> 1;

    f32x4 zf = {0.f, 0.f, 0.f, 0.f};
    f32x4 acc[4][4];
    #pragma unroll
    for (int i = 0; i < 4; ++i)
        #pragma unroll
        for (int j = 0; j < 4; ++j) acc[i][j] = zf;

    for (int kt = 0; kt < 12; ++kt) {
        __syncthreads();
        stage128x64(xb + (size_t)m0 * 768 + kt * 64, 768, As, wid, lane);
        stage128x64(wtg + (size_t)j0 * 768 + kt * 64, 768, Bs, wid, lane);
        __syncthreads();
        #pragma unroll
        for (int ks = 0; ks < 2; ++ks) {
            bf16x8 af[4], bfr[4];
            #pragma unroll
            for (int mi = 0; mi < 4; ++mi)
                af[mi] = frag(As, wr * 64 + mi * 16 + lrow, ks * 4 + quad);
            #pragma unroll
            for (int ni = 0; ni < 4; ++ni)
                bfr[ni] = frag(Bs, wc * 64 + ni * 16 + lrow, ks * 4 + quad);
            #pragma unroll
            for (int mi = 0; mi < 4; ++mi)
                #pragma unroll
                for (int ni = 0; ni < 4; ++ni)
                    acc[mi][ni] = mfma16(af[mi], bfr[ni], acc[mi][ni]);
        }
    }

    const int jw = j0 + wc * 64;
    const int mat = jw / 768;
    const int n = (jw % 768) >> 6;
    const int b = m0 >> 10;
    const int s_base = (m0 & 1023) + wr * 64;
    const float* bias = (mat == 0 ? bq : mat == 1 ? bk : bv) + n * 64;
    float bias_v[4];
    #pragma unroll
    for (int ni = 0; ni < 4; ++ni) bias_v[ni] = bias[ni * 16 + lrow];

    if (mat == 2) {
        __bf16* vout = Vtb + (size_t)(b * N_ + n) * 64 * 1024;
        #pragma unroll
        for (int mi = 0; mi < 4; ++mi)
            #pragma unroll
            for (int ni = 0; ni < 4; ++ni) {
                int h = ni * 16 + lrow;
                int s0 = s_base + mi * 16 + quad * 4;
                bf16x4 pv;
                #pragma unroll
                for (int r = 0; r < 4; ++r)
                    pv[r] = (__bf16)(acc[mi][ni][r] + bias_v[ni]);
                *(bf16x4*)(vout + (size_t)h * 1024 + s0) = pv;
            }
    } else {
        __bf16* qk = (mat == 0 ? Qb : Kb) + (size_t)(b * N_ + n) * 1024 * 64;
        #pragma unroll
        for (int mi = 0; mi < 4; ++mi)
            #pragma unroll
            for (int r = 0; r < 4; ++r) {
                int s = s_base + mi * 16 + quad * 4 + r;
                #pragma unroll
                for (int ni = 0; ni < 4; ++ni) {
                    int h = ni * 16 + lrow;
                    qk[(size_t)s * 64 + h] = (__bf16)(acc[mi][ni][r] + bias_v[ni]);
                }
            }
    }
}

// ---------------------------------------------------------------------------
// Flash attention v2: q-tile 128, K/V double-buffered prefetch, one barrier
// per K-tile. Wave w owns q rows [w*32, w*32+32) as two 16-row groups.
// Q fragments live in registers. Longest-first block order.
// ---------------------------------------------------------------------------
__global__ __launch_bounds__(256) void attn_mfma(
    const __bf16* __restrict__ Qb, const __bf16* __restrict__ Kb,
    const __bf16* __restrict__ Vtb, __bf16* __restrict__ zb) {
    __shared__ __bf16 Ks[2][64 * 64], Vs[2][64 * 64];
    __shared__ __bf16 Ps[4][2][16 * 64];
    const int bid = blockIdx.x;
    const int q8 = 7 - bid / 48;          // longest-first
    const int bn = bid % 48;
    const int b = bn / N_, n = bn % N_;
    const int tid = threadIdx.x, wid = tid >> 6, lane = tid & 63;
    const int quad = lane >> 4, lrow = lane & 15;
    const __bf16* Qg = Qb + (size_t)(b * N_ + n) * S_ * H_;
    const __bf16* Kg = Kb + (size_t)(b * N_ + n) * S_ * H_;
    const __bf16* Vg = Vtb + (size_t)(b * N_ + n) * H_ * S_;
    const int q0 = q8 * 128;
    const int last = 2 * q8 + 1;

    // Q fragments in registers: [g][ks]
    bf16x8 qf[2][2];
    #pragma unroll
    for (int g = 0; g < 2; ++g)
        #pragma unroll
        for (int ks = 0; ks < 2; ++ks)
            qf[g][ks] = *(const bf16x8*)&Qg[(size_t)(q0 + wid * 32 + g * 16 + lrow) * 64
                                            + (ks * 4 + quad) * 8];

    stage64x64(Kg, 64, Ks[0], wid, lane);
    stage64x64(Vg, 1024, Vs[0], wid, lane);

    f32x4 zf = {0.f, 0.f, 0.f, 0.f};
    f32x4 o[2][4];
    float m_r[2][4], l_r[2][4];
    #pragma unroll
    for (int g = 0; g < 2; ++g)
        #pragma unroll
        for (int i = 0; i < 4; ++i) {
            o[g][i] = zf;
            m_r[g][i] = -1e30f;
            l_r[g][i] = 0.f;
        }

    for (int kt = 0; kt <= last; ++kt) {
        const int cur = kt & 1;
        __syncthreads();   // tile kt loads complete (issued a full tile ago)
        if (kt < last) {
            stage64x64(Kg + (size_t)(kt + 1) * 64 * 64, 64, Ks[cur ^ 1], wid, lane);
            stage64x64(Vg + (kt + 1) * 64, 1024, Vs[cur ^ 1], wid, lane);
        }
        const int gq0 = q0 + wid * 32;
        const bool act[2]  = {gq0 >= kt * 64, true};   // g1 row-min > g0: act1 always if act0... guard anyway below
        const bool a0 = (gq0      >= kt * 64);
        const bool a1 = (gq0 + 16 >= kt * 64);
        if (!a0 && !a1) continue;                       // wave fully masked this tile
        (void)act;

        // K fragments (shared by both groups)
        bf16x8 kf[2][4];
        #pragma unroll
        for (int ks = 0; ks < 2; ++ks)
            #pragma unroll
            for (int nt = 0; nt < 4; ++nt)
                kf[ks][nt] = frag(Ks[cur], nt * 16 + lrow, ks * 4 + quad);

        f32x4 sc[2][4];
        #pragma unroll
        for (int g = 0; g < 2; ++g) {
            const bool ag = g == 0 ? a0 : a1;
            if (!ag) continue;
            #pragma unroll
            for (int nt = 0; nt < 4; ++nt) sc[g][nt] = zf;
            #pragma unroll
            for (int ks = 0; ks < 2; ++ks)
                #pragma unroll
                for (int nt = 0; nt < 4; ++nt)
                    sc[g][nt] = mfma16(qf[g][ks], kf[ks][nt], sc[g][nt]);
        }

        // mask + online softmax (exp2 domain) + P write, per group
        #pragma unroll
        for (int g = 0; g < 2; ++g) {
            const bool ag = g == 0 ? a0 : a1;
            if (!ag) continue;
            const int gq = gq0 + g * 16;
            const bool diag = gq < kt * 64 + 64;
            float alpha[4];
            #pragma unroll
            for (int r = 0; r < 4; ++r) {
                float v[4];
                #pragma unroll
                for (int nt = 0; nt < 4; ++nt) {
                    float s = sc[g][nt][r] * SCALE2;
                    if (diag && (kt * 64 + nt * 16 + lrow) > (gq + quad * 4 + r))
                        s = -1e30f;
                    v[nt] = s;
                }
                float mt = fmaxf(fmaxf(v[0], v[1]), fmaxf(v[2], v[3]));
                mt = fmaxf(mt, __shfl_xor(mt, 1));
                mt = fmaxf(mt, __shfl_xor(mt, 2));
                mt = fmaxf(mt, __shfl_xor(mt, 4));
                mt = fmaxf(mt, __shfl_xor(mt, 8));
                float mn = fmaxf(m_r[g][r], mt);
                alpha[r] = exp2f(m_r[g][r] - mn);
                m_r[g][r] = mn;
                float rs = 0.f;
                #pragma unroll
                for (int nt = 0; nt < 4; ++nt) {
                    float p = exp2f(v[nt] - mn);
                    sc[g][nt][r] = p;
                    rs += p;
                }
                rs += __shfl_xor(rs, 1);
                rs += __shfl_xor(rs, 2);
                rs += __shfl_xor(rs, 4);
                rs += __shfl_xor(rs, 8);
                l_r[g][r] = l_r[g][r] * alpha[r] + rs;
            }
            #pragma unroll
            for (int ht = 0; ht < 4; ++ht)
                #pragma unroll
                for (int r = 0; r < 4; ++r) o[g][ht][r] *= alpha[r];
            __bf16* Pg = Ps[wid][g];
            #pragma unroll
            for (int nt = 0; nt < 4; ++nt)
                #pragma unroll
                for (int r = 0; r < 4; ++r) {
                    int row = quad * 4 + r, col = nt * 16 + lrow;
                    int p = (col >> 3) ^ (row & 7);
                    Pg[row * 64 + p * 8 + (col & 7)] = (__bf16)sc[g][nt][r];
                }
        }

        // V fragments + PV for both groups
        bf16x8 vf[2][4];
        #pragma unroll
        for (int ks = 0; ks < 2; ++ks)
            #pragma unroll
            for (int ht = 0; ht < 4; ++ht)
                vf[ks][ht] = frag(Vs[cur], ht * 16 + lrow, ks * 4 + quad);
        #pragma unroll
        for (int g = 0; g < 2; ++g) {
            const bool ag = g == 0 ? a0 : a1;
            if (!ag) continue;
            #pragma unroll
            for (int ks = 0; ks < 2; ++ks) {
                bf16x8 ap = frag(Ps[wid][g], lrow, ks * 4 + quad);
                #pragma unroll
                for (int ht = 0; ht < 4; ++ht)
                    o[g][ht] = mfma16(ap, vf[ks][ht], o[g][ht]);
            }
        }
    }

    __bf16* zout = zb + (size_t)b * S_ * 768 + (size_t)n * 64;
    #pragma unroll
    for (int g = 0; g < 2; ++g)
        #pragma unroll
        for (int r = 0; r < 4; ++r) {
            float linv = 1.0f / l_r[g][r];
            int q = q0 + wid * 32 + g * 16 + quad * 4 + r;
            #pragma unroll
            for (int ht = 0; ht < 4; ++ht)
                zout[(size_t)q * 768 + ht * 16 + lrow] = (__bf16)(o[g][ht][r] * linv);
        }
}

// ---------------------------------------------------------------------------
// Output projection (unchanged).
// ---------------------------------------------------------------------------
__global__ __launch_bounds__(256) void out_gemm(
    const __bf16* __restrict__ zb, const __bf16* __restrict__ wot,
    const float* __restrict__ bo, float* __restrict__ out) {
    __shared__ __bf16 As[128 * 64];
    __shared__ __bf16 Bs[128 * 64];
    const int m0 = blockIdx.x * 128;
    const int j0 = blockIdx.y * 128;
    const int tid = threadIdx.x, wid = tid >> 6, lane = tid & 63;
    const int quad = lane >> 4, lrow = lane & 15;
    const int wr = wid & 1, wc = wid >> 1;

    f32x4 zf = {0.f, 0.f, 0.f, 0.f};
    f32x4 acc[4][4];
    #pragma unroll
    for (int i = 0; i < 4; ++i)
        #pragma unroll
        for (int j = 0; j < 4; ++j) acc[i][j] = zf;

    for (int kt = 0; kt < 12; ++kt) {
        __syncthreads();
        stage128x64(zb + (size_t)m0 * 768 + kt * 64, 768, As, wid, lane);
        stage128x64(wot + (size_t)j0 * 768 + kt * 64, 768, Bs, wid, lane);
        __syncthreads();
        #pragma unroll
        for (int ks = 0; ks < 2; ++ks) {
            bf16x8 af[4], bfr[4];
            #pragma unroll
            for (int mi = 0; mi < 4; ++mi)
                af[mi] = frag(As, wr * 64 + mi * 16 + lrow, ks * 4 + quad);
            #pragma unroll
            for (int ni = 0; ni < 4; ++ni)
                bfr[ni] = frag(Bs, wc * 64 + ni * 16 + lrow, ks * 4 + quad);
            #pragma unroll
            for (int mi = 0; mi < 4; ++mi)
                #pragma unroll
                for (int ni = 0; ni < 4; ++ni)
                    acc[mi][ni] = mfma16(af[mi], bfr[ni], acc[mi][ni]);
        }
    }

    float bias_v[4];
    #pragma unroll
    for (int ni = 0; ni < 4; ++ni) bias_v[ni] = bo[j0 + wc * 64 + ni * 16 + lrow];
    #pragma unroll
    for (int mi = 0; mi < 4; ++mi)
        #pragma unroll
        for (int r = 0; r < 4; ++r) {
            int m = m0 + wr * 64 + mi * 16 + quad * 4 + r;
            #pragma unroll
            for (int ni = 0; ni < 4; ++ni) {
                int j = j0 + wc * 64 + ni * 16 + lrow;
                out[(size_t)m * 768 + j] = acc[mi][ni][r] + bias_v[ni];
            }
        }
}

// ---------------------------------------------------------------------------
extern "C" void kernel_launch(void* const* d_in, const int* in_sizes, int n_in,
                              void* d_out, int out_size, void* d_ws, size_t ws_size,
                              hipStream_t stream) {
    const float* x  = (const float*)d_in[0];
    const float* wq = (const float*)d_in[1];
    const float* wk = (const float*)d_in[2];
    const float* wv = (const float*)d_in[3];
    const float* wo = (const float*)d_in[4];
    const float* bq = (const float*)d_in[5];
    const float* bk = (const float*)d_in[6];
    const float* bv = (const float*)d_in[7];
    const float* bo = (const float*)d_in[8];
    float* out = (float*)d_out;

    __bf16* p   = (__bf16*)d_ws;
    __bf16* xb  = p;  p += (size_t)4096 * 768;
    __bf16* wt  = p;  p += (size_t)2304 * 768;
    __bf16* wot = p;  p += (size_t)768 * 768;
    __bf16* Qb  = p;  p += (size_t)BNSH;
    __bf16* Kb  = p;  p += (size_t)BNSH;
    __bf16* Vtb = p;  p += (size_t)BNSH;
    __bf16* zb  = p;  p += (size_t)4096 * 768;

    prep_kernel<<<1344, 256, 0, stream>>>(x, wq, wk, wv, wo, xb, wt, wot);
    qkv_gemm<<<dim3(32, 18), 256, 0, stream>>>(xb, wt, bq, bk, bv, Qb, Kb, Vtb);
    attn_mfma<<<384, 256, 0, stream>>>(Qb, Kb, Vtb, zb);
    out_gemm<<<dim3(32, 6), 256, 0, stream>>>(zb, wot, bo, out);
}

// Round 4
// 147.098 us; speedup vs baseline: 1.3157x; 1.3157x over previous
//
#include <hip/hip_runtime.h>

typedef __bf16 bf16x8 __attribute__((ext_vector_type(8)));
typedef __bf16 bf16x4 __attribute__((ext_vector_type(4)));
typedef float  f32x4  __attribute__((ext_vector_type(4)));

constexpr int B_ = 4, S_ = 1024, D_ = 768, N_ = 12, H_ = 64;
constexpr int BNSH = B_ * N_ * S_ * H_;   // 3,145,728
constexpr float SCALE2 = 0.18033688011f;  // (1/sqrt(64)) * log2(e): exp2 domain

__device__ __forceinline__ f32x4 mfma16(bf16x8 a, bf16x8 b, f32x4 c) {
    return __builtin_amdgcn_mfma_f32_16x16x32_bf16(a, b, c, 0, 0, 0);
}

// async global->LDS, 16B per lane. HW dest = wave-uniform base + lane*16.
__device__ __forceinline__ void gload16(const __bf16* g, __bf16* l) {
    __builtin_amdgcn_global_load_lds(
        (const __attribute__((address_space(1))) unsigned int*)g,
        (__attribute__((address_space(3))) unsigned int*)l, 16, 0, 0);
}

// ---- LDS tile staging with 16B-chunk xor swizzle --------------------------
// Tiles are [rows][64] bf16. Global chunk (r, q) lands at LDS slot (r, q^(r&7)).
__device__ __forceinline__ void stage128x64(const __bf16* g, int ld, __bf16* lds,
                                            int wid, int lane) {
    #pragma unroll
    for (int i = 0; i < 4; ++i) {
        int cb = (wid * 4 + i) * 64;
        int chunk = cb + lane;
        int r = chunk >> 3, p = chunk & 7;
        int q = p ^ (r & 7);
        gload16(g + (size_t)r * ld + q * 8, lds + cb * 8);
    }
}
__device__ __forceinline__ void stage64x64(const __bf16* g, int ld, __bf16* lds,
                                           int wid, int lane) {
    #pragma unroll
    for (int i = 0; i < 2; ++i) {
        int cb = (wid * 2 + i) * 64;
        int chunk = cb + lane;
        int r = chunk >> 3, p = chunk & 7;
        int q = p ^ (r & 7);
        gload16(g + (size_t)r * ld + q * 8, lds + cb * 8);
    }
}

// ---- DPP 16-lane butterfly reductions (no LDS, pure VALU) -----------------
template <int CTRL>
__device__ __forceinline__ float dpp_mov(float x) {
    return __int_as_float(__builtin_amdgcn_update_dpp(
        0, __float_as_int(x), CTRL, 0xf, 0xf, true));
}
__device__ __forceinline__ float red16_max(float x) {
    x = fmaxf(x, dpp_mov<0xB1>(x));    // quad_perm [1,0,3,2]  (xor 1)
    x = fmaxf(x, dpp_mov<0x4E>(x));    // quad_perm [2,3,0,1]  (xor 2)
    x = fmaxf(x, dpp_mov<0x124>(x));   // row_ror:4
    x = fmaxf(x, dpp_mov<0x128>(x));   // row_ror:8
    return x;
}
__device__ __forceinline__ float red16_sum(float x) {
    x += dpp_mov<0xB1>(x);
    x += dpp_mov<0x4E>(x);
    x += dpp_mov<0x124>(x);
    x += dpp_mov<0x128>(x);
    return x;
}

// ---------------------------------------------------------------------------
// Fused prep: cast x -> bf16; transpose-cast W_QKV -> [2304][768]; W_O -> B^T.
// blocks [0,768): x cast; [768,1200): wqkv; [1200,1344): wo.
// ---------------------------------------------------------------------------
__global__ __launch_bounds__(256) void prep_kernel(
    const float* __restrict__ x,
    const float* __restrict__ wq, const float* __restrict__ wk,
    const float* __restrict__ wv, const float* __restrict__ wo,
    __bf16* __restrict__ xb, __bf16* __restrict__ wt, __bf16* __restrict__ wot) {
    __shared__ __bf16 T[64][65];
    const int blk = blockIdx.x;
    const int tid = threadIdx.x;
    if (blk < 768) {
        int base = blk * 1024 + tid;
        #pragma unroll
        for (int i = 0; i < 4; ++i) {
            int idx = base + i * 256;
            float4 v = ((const float4*)x)[idx];
            bf16x4 o;
            o[0] = (__bf16)v.x; o[1] = (__bf16)v.y;
            o[2] = (__bf16)v.z; o[3] = (__bf16)v.w;
            ((bf16x4*)xb)[idx] = o;
        }
        return;
    }
    int rr = tid >> 4, c4 = (tid & 15) * 4;
    if (blk < 1200) {
        int t = blk - 768;
        int dt = t % 12, mh = t / 12;
        int mat = mh / 12, n = mh % 12;
        const float* in = (mat == 0 ? wq : mat == 1 ? wk : wv) + (size_t)n * 768 * 64;
        __bf16* outp = wt + (size_t)(mat * 768 + n * 64) * 768;
        int d0 = dt * 64;
        #pragma unroll
        for (int i = 0; i < 4; ++i) {
            int row = rr + 16 * i;
            float4 v = *(const float4*)&in[(size_t)(d0 + row) * 64 + c4];
            T[c4 + 0][row] = (__bf16)v.x;
            T[c4 + 1][row] = (__bf16)v.y;
            T[c4 + 2][row] = (__bf16)v.z;
            T[c4 + 3][row] = (__bf16)v.w;
        }
        __syncthreads();
        #pragma unroll
        for (int i = 0; i < 4; ++i) {
            int hrow = rr + 16 * i;
            bf16x4 o;
            o[0] = T[hrow][c4 + 0]; o[1] = T[hrow][c4 + 1];
            o[2] = T[hrow][c4 + 2]; o[3] = T[hrow][c4 + 3];
            *(bf16x4*)&outp[(size_t)hrow * 768 + d0 + c4] = o;
        }
    } else {
        int t = blk - 1200;
        int r0 = (t % 12) * 64, c0 = (t / 12) * 64;
        #pragma unroll
        for (int i = 0; i < 4; ++i) {
            int row = rr + 16 * i;
            float4 v = *(const float4*)&wo[(size_t)(r0 + row) * 768 + c0 + c4];
            T[c4 + 0][row] = (__bf16)v.x;
            T[c4 + 1][row] = (__bf16)v.y;
            T[c4 + 2][row] = (__bf16)v.z;
            T[c4 + 3][row] = (__bf16)v.w;
        }
        __syncthreads();
        #pragma unroll
        for (int i = 0; i < 4; ++i) {
            int crow = rr + 16 * i;
            bf16x4 o;
            o[0] = T[crow][c4 + 0]; o[1] = T[crow][c4 + 1];
            o[2] = T[crow][c4 + 2]; o[3] = T[crow][c4 + 3];
            *(bf16x4*)&wot[(size_t)(c0 + crow) * 768 + r0 + c4] = o;
        }
    }
}

// ---------------------------------------------------------------------------
// QKV GEMM: tile 128x64, BK=64, double-buffered (one barrier per K-tile).
// 4 waves; wave wid owns rows [wid*32, wid*32+32), full 64 cols of j-tile.
// j-tile of 64 == exactly one (mat, head). Writes Q,K [B,N,S,H]; V^T [B,N,H,S].
// ---------------------------------------------------------------------------
__global__ __launch_bounds__(256) void qkv_gemm(
    const __bf16* __restrict__ xb, const __bf16* __restrict__ wtg,
    const float* __restrict__ bq, const float* __restrict__ bk,
    const float* __restrict__ bv,
    __bf16* __restrict__ Qb, __bf16* __restrict__ Kb, __bf16* __restrict__ Vtb) {
    __shared__ __bf16 As[2][128 * 64];
    __shared__ __bf16 Bs[2][64 * 64];
    const int m0 = blockIdx.x * 128;
    const int j0 = blockIdx.y * 64;
    const int tid = threadIdx.x, wid = tid >> 6, lane = tid & 63;
    const int quad = lane >> 4, lrow = lane & 15;
    const int l3 = lrow & 7;
    int koff[2];
    #pragma unroll
    for (int ks = 0; ks < 2; ++ks)
        koff[ks] = lrow * 64 + ((ks * 4 + quad) ^ l3) * 8;

    f32x4 zf = {0.f, 0.f, 0.f, 0.f};
    f32x4 acc[2][4];
    #pragma unroll
    for (int i = 0; i < 2; ++i)
        #pragma unroll
        for (int j = 0; j < 4; ++j) acc[i][j] = zf;

    stage128x64(xb + (size_t)m0 * 768, 768, As[0], wid, lane);
    stage64x64(wtg + (size_t)j0 * 768, 768, Bs[0], wid, lane);

    for (int kt = 0; kt < 12; ++kt) {
        const int buf = kt & 1;
        __syncthreads();
        if (kt < 11) {
            stage128x64(xb + (size_t)m0 * 768 + (kt + 1) * 64, 768, As[buf ^ 1], wid, lane);
            stage64x64(wtg + (size_t)j0 * 768 + (kt + 1) * 64, 768, Bs[buf ^ 1], wid, lane);
        }
        #pragma unroll
        for (int ks = 0; ks < 2; ++ks) {
            bf16x8 af[2], bfr[4];
            #pragma unroll
            for (int mi = 0; mi < 2; ++mi)
                af[mi] = *(const bf16x8*)(As[buf] + (wid * 32 + mi * 16) * 64 + koff[ks]);
            #pragma unroll
            for (int ni = 0; ni < 4; ++ni)
                bfr[ni] = *(const bf16x8*)(Bs[buf] + ni * 1024 + koff[ks]);
            #pragma unroll
            for (int mi = 0; mi < 2; ++mi)
                #pragma unroll
                for (int ni = 0; ni < 4; ++ni)
                    acc[mi][ni] = mfma16(af[mi], bfr[ni], acc[mi][ni]);
        }
    }

    const int mat = j0 / 768;
    const int n = (j0 % 768) >> 6;
    const int b = m0 >> 10;
    const int s_base = (m0 & 1023) + wid * 32;
    const float* bias = (mat == 0 ? bq : mat == 1 ? bk : bv) + n * 64;
    float bias_v[4];
    #pragma unroll
    for (int ni = 0; ni < 4; ++ni) bias_v[ni] = bias[ni * 16 + lrow];

    if (mat == 2) {
        __bf16* vout = Vtb + (size_t)(b * N_ + n) * 64 * 1024;
        #pragma unroll
        for (int mi = 0; mi < 2; ++mi)
            #pragma unroll
            for (int ni = 0; ni < 4; ++ni) {
                int h = ni * 16 + lrow;
                int s0 = s_base + mi * 16 + quad * 4;
                bf16x4 pv;
                #pragma unroll
                for (int r = 0; r < 4; ++r)
                    pv[r] = (__bf16)(acc[mi][ni][r] + bias_v[ni]);
                *(bf16x4*)(vout + (size_t)h * 1024 + s0) = pv;
            }
    } else {
        __bf16* qk = (mat == 0 ? Qb : Kb) + (size_t)(b * N_ + n) * 1024 * 64;
        #pragma unroll
        for (int mi = 0; mi < 2; ++mi)
            #pragma unroll
            for (int r = 0; r < 4; ++r) {
                int s = s_base + mi * 16 + quad * 4 + r;
                #pragma unroll
                for (int ni = 0; ni < 4; ++ni)
                    qk[(size_t)s * 64 + ni * 16 + lrow] =
                        (__bf16)(acc[mi][ni][r] + bias_v[ni]);
            }
    }
}

// ---------------------------------------------------------------------------
// Flash attention v3: q-tile 64 (768 blocks, longest-first), K/V double-
// buffered single-barrier pipeline, DPP softmax reductions, hoisted offsets.
// Wave wid owns q rows [wid*16, wid*16+16). z written as [B][S][N*H] bf16.
// ---------------------------------------------------------------------------
__global__ __launch_bounds__(256) void attn_mfma(
    const __bf16* __restrict__ Qb, const __bf16* __restrict__ Kb,
    const __bf16* __restrict__ Vtb, __bf16* __restrict__ zb) {
    __shared__ __bf16 Ks[2][64 * 64], Vs[2][64 * 64];
    __shared__ __bf16 Ps[4][16 * 64];
    const int bid = blockIdx.x;
    const int qt = 15 - bid / 48;          // longest-first
    const int bn = bid % 48;
    const int b = bn / N_, n = bn % N_;
    const int tid = threadIdx.x, wid = tid >> 6, lane = tid & 63;
    const int quad = lane >> 4, lrow = lane & 15;
    const int l3 = lrow & 7;
    const __bf16* Qg = Qb + (size_t)(b * N_ + n) * S_ * H_;
    const __bf16* Kg = Kb + (size_t)(b * N_ + n) * S_ * H_;
    const __bf16* Vg = Vtb + (size_t)(b * N_ + n) * H_ * S_;
    const int q0 = qt * 64;

    // loop-invariant LDS element offsets
    int koff[2];
    #pragma unroll
    for (int ks = 0; ks < 2; ++ks)
        koff[ks] = lrow * 64 + ((ks * 4 + quad) ^ l3) * 8;
    int pw[4][4];
    #pragma unroll
    for (int nt = 0; nt < 4; ++nt)
        #pragma unroll
        for (int r = 0; r < 4; ++r) {
            int row = quad * 4 + r, col = nt * 16 + lrow;
            pw[nt][r] = row * 64 + ((col >> 3) ^ (row & 7)) * 8 + (col & 7);
        }

    // Q fragments in registers
    bf16x8 qf[2];
    #pragma unroll
    for (int ks = 0; ks < 2; ++ks)
        qf[ks] = *(const bf16x8*)&Qg[(size_t)(q0 + wid * 16 + lrow) * 64
                                     + (ks * 4 + quad) * 8];

    stage64x64(Kg, 64, Ks[0], wid, lane);
    stage64x64(Vg, 1024, Vs[0], wid, lane);

    f32x4 zf = {0.f, 0.f, 0.f, 0.f};
    f32x4 o[4];
    float m_r[4], l_r[4];
    #pragma unroll
    for (int i = 0; i < 4; ++i) { o[i] = zf; m_r[i] = -1e30f; l_r[i] = 0.f; }
    __bf16* Pw = Ps[wid];

    auto do_tile = [&](int buf, bool diag) {
        // QK^T scores
        f32x4 sc[4];
        #pragma unroll
        for (int nt = 0; nt < 4; ++nt) sc[nt] = zf;
        #pragma unroll
        for (int ks = 0; ks < 2; ++ks) {
            #pragma unroll
            for (int nt = 0; nt < 4; ++nt) {
                bf16x8 kf = *(const bf16x8*)(Ks[buf] + nt * 1024 + koff[ks]);
                sc[nt] = mfma16(qf[ks], kf, sc[nt]);
            }
        }
        float v[4][4];
        #pragma unroll
        for (int nt = 0; nt < 4; ++nt)
            #pragma unroll
            for (int r = 0; r < 4; ++r) v[nt][r] = sc[nt][r] * SCALE2;
        if (diag) {
            #pragma unroll
            for (int nt = 0; nt < 4; ++nt)
                #pragma unroll
                for (int r = 0; r < 4; ++r)
                    if ((nt * 16 + lrow) > (wid * 16 + quad * 4 + r))
                        v[nt][r] = -1e30f;
        }
        // online softmax (exp2 domain), DPP reductions
        float alpha[4];
        #pragma unroll
        for (int r = 0; r < 4; ++r) {
            float mt = fmaxf(fmaxf(v[0][r], v[1][r]), fmaxf(v[2][r], v[3][r]));
            mt = red16_max(mt);
            float mn = fmaxf(m_r[r], mt);
            alpha[r] = exp2f(m_r[r] - mn);
            m_r[r] = mn;
            float rs = 0.f;
            #pragma unroll
            for (int nt = 0; nt < 4; ++nt) {
                float p = exp2f(v[nt][r] - mn);
                v[nt][r] = p;
                rs += p;
            }
            rs = red16_sum(rs);
            l_r[r] = l_r[r] * alpha[r] + rs;
        }
        #pragma unroll
        for (int ht = 0; ht < 4; ++ht)
            #pragma unroll
            for (int r = 0; r < 4; ++r) o[ht][r] *= alpha[r];
        // P -> wave-private LDS strip (bf16, swizzled)
        #pragma unroll
        for (int nt = 0; nt < 4; ++nt)
            #pragma unroll
            for (int r = 0; r < 4; ++r) Pw[pw[nt][r]] = (__bf16)v[nt][r];
        // PV
        #pragma unroll
        for (int ks = 0; ks < 2; ++ks) {
            bf16x8 ap = *(const bf16x8*)(Pw + koff[ks]);
            #pragma unroll
            for (int ht = 0; ht < 4; ++ht) {
                bf16x8 vf = *(const bf16x8*)(Vs[buf] + ht * 1024 + koff[ks]);
                o[ht] = mfma16(ap, vf, o[ht]);
            }
        }
    };

    for (int kt = 0; kt < qt; ++kt) {
        __syncthreads();
        stage64x64(Kg + (size_t)(kt + 1) * 64 * 64, 64, Ks[(kt + 1) & 1], wid, lane);
        stage64x64(Vg + (kt + 1) * 64, 1024, Vs[(kt + 1) & 1], wid, lane);
        do_tile(kt & 1, false);
    }
    __syncthreads();
    do_tile(qt & 1, true);

    __bf16* zout = zb + (size_t)b * S_ * 768 + (size_t)n * 64;
    #pragma unroll
    for (int r = 0; r < 4; ++r) {
        float linv = 1.0f / l_r[r];
        int q = q0 + wid * 16 + quad * 4 + r;
        #pragma unroll
        for (int ht = 0; ht < 4; ++ht)
            zout[(size_t)q * 768 + ht * 16 + lrow] = (__bf16)(o[ht][r] * linv);
    }
}

// ---------------------------------------------------------------------------
// Output projection: tile 128x64, BK=64, double-buffered. fp32 out + bias.
// ---------------------------------------------------------------------------
__global__ __launch_bounds__(256) void out_gemm(
    const __bf16* __restrict__ zb, const __bf16* __restrict__ wot,
    const float* __restrict__ bo, float* __restrict__ out) {
    __shared__ __bf16 As[2][128 * 64];
    __shared__ __bf16 Bs[2][64 * 64];
    const int m0 = blockIdx.x * 128;
    const int j0 = blockIdx.y * 64;
    const int tid = threadIdx.x, wid = tid >> 6, lane = tid & 63;
    const int quad = lane >> 4, lrow = lane & 15;
    const int l3 = lrow & 7;
    int koff[2];
    #pragma unroll
    for (int ks = 0; ks < 2; ++ks)
        koff[ks] = lrow * 64 + ((ks * 4 + quad) ^ l3) * 8;

    f32x4 zf = {0.f, 0.f, 0.f, 0.f};
    f32x4 acc[2][4];
    #pragma unroll
    for (int i = 0; i < 2; ++i)
        #pragma unroll
        for (int j = 0; j < 4; ++j) acc[i][j] = zf;

    stage128x64(zb + (size_t)m0 * 768, 768, As[0], wid, lane);
    stage64x64(wot + (size_t)j0 * 768, 768, Bs[0], wid, lane);

    for (int kt = 0; kt < 12; ++kt) {
        const int buf = kt & 1;
        __syncthreads();
        if (kt < 11) {
            stage128x64(zb + (size_t)m0 * 768 + (kt + 1) * 64, 768, As[buf ^ 1], wid, lane);
            stage64x64(wot + (size_t)j0 * 768 + (kt + 1) * 64, 768, Bs[buf ^ 1], wid, lane);
        }
        #pragma unroll
        for (int ks = 0; ks < 2; ++ks) {
            bf16x8 af[2], bfr[4];
            #pragma unroll
            for (int mi = 0; mi < 2; ++mi)
                af[mi] = *(const bf16x8*)(As[buf] + (wid * 32 + mi * 16) * 64 + koff[ks]);
            #pragma unroll
            for (int ni = 0; ni < 4; ++ni)
                bfr[ni] = *(const bf16x8*)(Bs[buf] + ni * 1024 + koff[ks]);
            #pragma unroll
            for (int mi = 0; mi < 2; ++mi)
                #pragma unroll
                for (int ni = 0; ni < 4; ++ni)
                    acc[mi][ni] = mfma16(af[mi], bfr[ni], acc[mi][ni]);
        }
    }

    float bias_v[4];
    #pragma unroll
    for (int ni = 0; ni < 4; ++ni) bias_v[ni] = bo[j0 + ni * 16 + lrow];
    #pragma unroll
    for (int mi = 0; mi < 2; ++mi)
        #pragma unroll
        for (int r = 0; r < 4; ++r) {
            int m = m0 + wid * 32 + mi * 16 + quad * 4 + r;
            #pragma unroll
            for (int ni = 0; ni < 4; ++ni)
                out[(size_t)m * 768 + j0 + ni * 16 + lrow] =
                    acc[mi][ni][r] + bias_v[ni];
        }
}

// ---------------------------------------------------------------------------
extern "C" void kernel_launch(void* const* d_in, const int* in_sizes, int n_in,
                              void* d_out, int out_size, void* d_ws, size_t ws_size,
                              hipStream_t stream) {
    const float* x  = (const float*)d_in[0];
    const float* wq = (const float*)d_in[1];
    const float* wk = (const float*)d_in[2];
    const float* wv = (const float*)d_in[3];
    const float* wo = (const float*)d_in[4];
    const float* bq = (const float*)d_in[5];
    const float* bk = (const float*)d_in[6];
    const float* bv = (const float*)d_in[7];
    const float* bo = (const float*)d_in[8];
    float* out = (float*)d_out;

    __bf16* p   = (__bf16*)d_ws;
    __bf16* xb  = p;  p += (size_t)4096 * 768;
    __bf16* wt  = p;  p += (size_t)2304 * 768;
    __bf16* wot = p;  p += (size_t)768 * 768;
    __bf16* Qb  = p;  p += (size_t)BNSH;
    __bf16* Kb  = p;  p += (size_t)BNSH;
    __bf16* Vtb = p;  p += (size_t)BNSH;
    __bf16* zb  = p;  p += (size_t)4096 * 768;

    prep_kernel<<<1344, 256, 0, stream>>>(x, wq, wk, wv, wo, xb, wt, wot);
    qkv_gemm<<<dim3(32, 36), 256, 0, stream>>>(xb, wt, bq, bk, bv, Qb, Kb, Vtb);
    attn_mfma<<<768, 256, 0, stream>>>(Qb, Kb, Vtb, zb);
    out_gemm<<<dim3(32, 12), 256, 0, stream>>>(zb, wot, bo, out);
}